// Round 1
// baseline (806.065 us; speedup 1.0000x reference)
//
#include <hip/hip_runtime.h>
#include <math.h>

typedef __bf16 bf16;
typedef __bf16 bf16x8 __attribute__((ext_vector_type(8)));
typedef float f32x4 __attribute__((ext_vector_type(4)));

// ---------------- staging: 16 elements global -> LDS (convert f32->bf16 if needed)
template<typename T>
__device__ inline void stage16(const T* __restrict__ s, bf16* __restrict__ dst) {
  if constexpr (sizeof(T) == 4) {
    f32x4 v0 = *(const f32x4*)(s);
    f32x4 v1 = *(const f32x4*)(s + 4);
    f32x4 v2 = *(const f32x4*)(s + 8);
    f32x4 v3 = *(const f32x4*)(s + 12);
    bf16x8 lo, hi;
#pragma unroll
    for (int j = 0; j < 4; ++j) {
      lo[j]     = (bf16)v0[j];
      lo[j + 4] = (bf16)v1[j];
      hi[j]     = (bf16)v2[j];
      hi[j + 4] = (bf16)v3[j];
    }
    *(bf16x8*)dst       = lo;
    *(bf16x8*)(dst + 8) = hi;
  } else {
    *(bf16x8*)dst       = *(const bf16x8*)s;
    *(bf16x8*)(dst + 8) = *(const bf16x8*)(s + 8);
  }
}

// ---------------- generic GEMM: C[m][n] = op( scale * sum_k A[m][k]*B[n][k] + bias +/- mask )
// A: [M][K] row-major (f32 or bf16). B: [N][K] row-major (f32 or bf16).
// BIAS_MODE: 0 none, 1 per-col(n), 2 per-row(m). MASK: add -1e9*maskT[m][n].
// 128x128 tile, BK=32, 256 threads = 4 waves (2x2 of 64x64), mfma 16x16x32 bf16.
template<typename TA, typename TB, int BIAS_MODE, bool MASK, bool GELU, bool OUT_BF16>
__global__ __launch_bounds__(256)
void gemm_k(const TA* __restrict__ A, const TB* __restrict__ B,
            const float* __restrict__ bias, const signed char* __restrict__ mT,
            void* __restrict__ Cout, int M, int N, int K,
            long sAb, long sBb, long sCb, long sMb, float scale)
{
  __shared__ bf16 As[128][40];  // +8 pad: stride 80B = 20 dwords -> conflict-free-ish
  __shared__ bf16 Bs[128][40];
  const int t  = threadIdx.x;
  const int zb = blockIdx.z;
  const int m0 = blockIdx.y * 128;
  const int n0 = blockIdx.x * 128;
  const TA* Ab = A + (size_t)zb * sAb + (size_t)m0 * K;
  const TB* Bb = B + (size_t)zb * sBb + (size_t)n0 * K;

  const int srow = t >> 1;           // 0..127
  const int scol = (t & 1) << 4;     // 0 or 16

  f32x4 acc[4][4] = {};

  const int wave = t >> 6;
  const int lane = t & 63;
  const int wm = (wave >> 1) << 6;   // 0 or 64
  const int wn = (wave & 1) << 6;    // 0 or 64
  const int fr = lane & 15;
  const int fg = lane >> 4;          // 0..3

  for (int k0 = 0; k0 < K; k0 += 32) {
    stage16(Ab + (size_t)srow * K + k0 + scol, &As[srow][scol]);
    stage16(Bb + (size_t)srow * K + k0 + scol, &Bs[srow][scol]);
    __syncthreads();
    bf16x8 af[4], bfv[4];
#pragma unroll
    for (int i = 0; i < 4; ++i) af[i]  = *(const bf16x8*)&As[wm + i * 16 + fr][fg * 8];
#pragma unroll
    for (int i = 0; i < 4; ++i) bfv[i] = *(const bf16x8*)&Bs[wn + i * 16 + fr][fg * 8];
#pragma unroll
    for (int mi = 0; mi < 4; ++mi)
#pragma unroll
      for (int ni = 0; ni < 4; ++ni)
        acc[mi][ni] = __builtin_amdgcn_mfma_f32_16x16x32_bf16(af[mi], bfv[ni], acc[mi][ni], 0, 0, 0);
    __syncthreads();
  }

  const signed char* mb = mT + (size_t)zb * sMb;
#pragma unroll
  for (int mi = 0; mi < 4; ++mi) {
#pragma unroll
    for (int ni = 0; ni < 4; ++ni) {
      const int col = n0 + wn + ni * 16 + fr;
#pragma unroll
      for (int i = 0; i < 4; ++i) {
        const int r = m0 + wm + mi * 16 + fg * 4 + i;   // C/D: row=(lane>>4)*4+i, col=lane&15
        float v = acc[mi][ni][i] * scale;
        if constexpr (BIAS_MODE == 1) v += bias[col];
        if constexpr (BIAS_MODE == 2) v += bias[r];
        if constexpr (MASK) v += -1e9f * (float)mb[(size_t)r * N + col];
        if constexpr (GELU) v = 0.5f * v * (1.0f + erff(v * 0.70710678118f));
        const size_t off = (size_t)zb * sCb + (size_t)r * N + col;
        if constexpr (OUT_BF16) ((bf16*)Cout)[off] = (bf16)v;
        else                    ((float*)Cout)[off] = v;
      }
    }
  }
}

// ---------------- weight transpose+convert: out[n][k] = (bf16)W[k][n], 1024x1024, z selects weight
__global__ __launch_bounds__(256)
void wtrans_k(const float* __restrict__ W0, const float* __restrict__ W1,
              const float* __restrict__ W2, const float* __restrict__ W3,
              bf16* __restrict__ out)
{
  const float* Ws[4] = {W0, W1, W2, W3};
  const float* W = Ws[blockIdx.z];
  bf16* o = out + (size_t)blockIdx.z * (1024 * 1024);
  __shared__ bf16 tile[64][72];
  const int t  = threadIdx.x;
  const int c0 = blockIdx.x * 64;   // column of W = output row n
  const int r0 = blockIdx.y * 64;   // row of W = k
  {
    const int rr = t >> 2;
    const int cc = (t & 3) * 16;
    const float* src = W + (size_t)(r0 + rr) * 1024 + c0 + cc;
#pragma unroll
    for (int j = 0; j < 16; j += 4) {
      f32x4 v = *(const f32x4*)(src + j);
#pragma unroll
      for (int i = 0; i < 4; ++i) tile[cc + j + i][rr] = (bf16)v[i];
    }
  }
  __syncthreads();
  {
    const int nr = t >> 2;
    const int kc = (t & 3) * 16;
    bf16* dst = o + (size_t)(c0 + nr) * 1024 + r0 + kc;
    bf16x8 a = *(const bf16x8*)&tile[nr][kc];
    bf16x8 b = *(const bf16x8*)&tile[nr][kc + 8];
    *(bf16x8*)dst       = a;
    *(bf16x8*)(dst + 8) = b;
  }
}

// ---------------- mask transpose: maskT[b][k][q] = (int8)mask[b][q][k]
__global__ __launch_bounds__(256)
void maskT_k(const int* __restrict__ mask, signed char* __restrict__ mT)
{
  __shared__ signed char tile[64][65];
  const int t  = threadIdx.x;
  const int b  = blockIdx.z;
  const int k0 = blockIdx.x * 64;
  const int q0 = blockIdx.y * 64;
  {
    const int iq = t >> 2;
    const int ic = (t & 3) * 16;
    const int* src = mask + ((size_t)b * 2048 + q0 + iq) * 2048 + k0 + ic;
#pragma unroll
    for (int j = 0; j < 16; j += 4) {
      int4 v = *(const int4*)(src + j);
      tile[ic + j + 0][iq] = (signed char)v.x;
      tile[ic + j + 1][iq] = (signed char)v.y;
      tile[ic + j + 2][iq] = (signed char)v.z;
      tile[ic + j + 3][iq] = (signed char)v.w;
    }
  }
  __syncthreads();
  {
    const int ik = t >> 2;
    const int iq = (t & 3) * 16;
    signed char* dst = mT + ((size_t)b * 2048 + k0 + ik) * 2048 + q0 + iq;
#pragma unroll
    for (int j = 0; j < 16; ++j) dst[j] = tile[ik][iq + j];
  }
}

// ---------------- in-place row softmax over 2048 columns (one block per row)
__global__ __launch_bounds__(256)
void softmax_rows_k(float* __restrict__ P)
{
  float* p = P + (size_t)blockIdx.x * 2048;
  const int t = threadIdx.x;
  const int wave = t >> 6, lane = t & 63;
  f32x4 v0 = *(const f32x4*)(p + t * 4);
  f32x4 v1 = *(const f32x4*)(p + 1024 + t * 4);
  float m = -3e38f;
#pragma unroll
  for (int j = 0; j < 4; ++j) { m = fmaxf(m, v0[j]); m = fmaxf(m, v1[j]); }
#pragma unroll
  for (int off = 32; off; off >>= 1) m = fmaxf(m, __shfl_xor(m, off));
  __shared__ float red[8];
  if (lane == 0) red[wave] = m;
  __syncthreads();
  m = fmaxf(fmaxf(red[0], red[1]), fmaxf(red[2], red[3]));
  float s = 0.0f;
#pragma unroll
  for (int j = 0; j < 4; ++j) {
    v0[j] = __expf(v0[j] - m); s += v0[j];
    v1[j] = __expf(v1[j] - m); s += v1[j];
  }
#pragma unroll
  for (int off = 32; off; off >>= 1) s += __shfl_xor(s, off);
  if (lane == 0) red[4 + wave] = s;
  __syncthreads();
  s = red[4] + red[5] + red[6] + red[7];
  const float inv = 1.0f / s;
#pragma unroll
  for (int j = 0; j < 4; ++j) { v0[j] *= inv; v1[j] *= inv; }
  *(f32x4*)(p + t * 4)        = v0;
  *(f32x4*)(p + 1024 + t * 4) = v1;
}

// ---------------- LayerNorm over 1024 (one block per row)
__global__ __launch_bounds__(256)
void ln_k(const float* __restrict__ g, const float* __restrict__ gamma,
          const float* __restrict__ beta, float* __restrict__ out)
{
  const float* p = g + (size_t)blockIdx.x * 1024;
  const int t = threadIdx.x;
  const int wave = t >> 6, lane = t & 63;
  f32x4 v = *(const f32x4*)(p + t * 4);
  float s = v[0] + v[1] + v[2] + v[3];
  float q = v[0]*v[0] + v[1]*v[1] + v[2]*v[2] + v[3]*v[3];
#pragma unroll
  for (int off = 32; off; off >>= 1) { s += __shfl_xor(s, off); q += __shfl_xor(q, off); }
  __shared__ float red[16];
  if (lane == 0) { red[wave] = s; red[8 + wave] = q; }
  __syncthreads();
  s = red[0] + red[1] + red[2] + red[3];
  q = red[8] + red[9] + red[10] + red[11];
  const float mu   = s * (1.0f / 1024.0f);
  const float var  = q * (1.0f / 1024.0f) - mu * mu;
  const float rstd = rsqrtf(var + 1e-5f);
  f32x4 gm = *(const f32x4*)(gamma + t * 4);
  f32x4 bt = *(const f32x4*)(beta + t * 4);
  f32x4 o;
#pragma unroll
  for (int j = 0; j < 4; ++j) o[j] = (v[j] - mu) * rstd * gm[j] + bt[j];
  *(f32x4*)(out + (size_t)blockIdx.x * 1024 + t * 4) = o;
}

extern "C" void kernel_launch(void* const* d_in, const int* in_sizes, int n_in,
                              void* d_out, int out_size, void* d_ws, size_t ws_size,
                              hipStream_t stream)
{
  const float* Q     = (const float*)d_in[0];
  const float* Kin   = (const float*)d_in[1];
  const float* V     = (const float*)d_in[2];
  const int*   mask  = (const int*)d_in[3];
  const float* Wq    = (const float*)d_in[4];
  const float* bq    = (const float*)d_in[5];
  const float* Wk    = (const float*)d_in[6];
  const float* bk    = (const float*)d_in[7];
  const float* Wv    = (const float*)d_in[8];
  const float* bv    = (const float*)d_in[9];
  const float* Wo    = (const float*)d_in[10];
  const float* bo    = (const float*)d_in[11];
  const float* gamma = (const float*)d_in[12];
  const float* beta  = (const float*)d_in[13];

  float* outCtx  = (float*)d_out;                              // [8,2048,1024]
  float* outAttn = outCtx + (size_t)8 * 2048 * 1024;           // [8,2048,2048] (k,q)

  // workspace layout (bytes):
  // [0, 32M)   qp bf16 [16384][1024]     | later: g f32 [16384][1024] spans [0,64M)
  // [32M,64M)  kp bf16 [16384][1024]
  // [64M,96M)  wvT bf16 [8][1024][2048]
  // [96M,128M) maskT int8 [8][2048][2048] | later: ctx bf16 [16384][1024]
  // [128M,136M) 4x bf16 transposed weights 1024x1024
  char* ws = (char*)d_ws;
  bf16*        qp  = (bf16*)(ws + 0);
  bf16*        kp  = (bf16*)(ws + 33554432);
  bf16*        wvT = (bf16*)(ws + 67108864);
  signed char* mT  = (signed char*)(ws + 100663296);
  bf16*        ctx = (bf16*)(ws + 100663296);       // aliases mT (mT dead after QK^T)
  float*       g   = (float*)(ws + 0);              // aliases qp+kp (dead after QK^T)
  bf16*        wts = (bf16*)(ws + 134217728);
  bf16* Wqt = wts;
  bf16* Wkt = wts + 1 * 1024 * 1024;
  bf16* Wvt = wts + 2 * 1024 * 1024;
  bf16* Wot = wts + 3 * 1024 * 1024;

  const dim3 blk(256);

  // 1. weight transpose+convert (4 weights via z)
  wtrans_k<<<dim3(16, 16, 4), blk, 0, stream>>>(Wq, Wk, Wv, Wo, wts);
  // 2. mask transpose -> int8 [b][k][q]
  maskT_k<<<dim3(32, 32, 8), blk, 0, stream>>>(mask, mT);
  // 3. qp = Q @ Wq + bq   (A f32, B=Wqt bf16, bias per-n, out bf16)
  gemm_k<float, bf16, 1, false, false, true><<<dim3(8, 128, 1), blk, 0, stream>>>(
      Q, Wqt, bq, nullptr, qp, 16384, 1024, 1024, 0, 0, 0, 0, 1.0f);
  // 4. kp = K @ Wk + bk
  gemm_k<float, bf16, 1, false, false, true><<<dim3(8, 128, 1), blk, 0, stream>>>(
      Kin, Wkt, bk, nullptr, kp, 16384, 1024, 1024, 0, 0, 0, 0, 1.0f);
  // 5. wvT[b][v][q] = (V@Wv+bv)^T  == Wv^T @ V^T   (A=Wvt bf16 [v][d], B=V f32 [q][d], bias per-m)
  gemm_k<bf16, float, 2, false, false, true><<<dim3(16, 8, 8), blk, 0, stream>>>(
      Wvt, V, bv, nullptr, wvT, 1024, 2048, 1024,
      0, (long)2048 * 1024, (long)1024 * 2048, 0, 1.0f);
  // 6. T[b][k][q] = kp[k]·qp[q] / 32 - 1e9*maskT  -> d_out attn region (f32)
  gemm_k<bf16, bf16, 0, true, false, false><<<dim3(16, 16, 8), blk, 0, stream>>>(
      kp, qp, nullptr, mT, outAttn, 2048, 2048, 1024,
      (long)2048 * 1024, (long)2048 * 1024, (long)2048 * 2048, (long)2048 * 2048, 0.03125f);
  // 7. row softmax in place (rows = B*L = 16384, each 2048 wide)
  softmax_rows_k<<<dim3(16384), blk, 0, stream>>>(outAttn);
  // 8. ctx[b][k][v] = sum_q attn[b][k][q] * wvT[b][v][q]   (A f32 = attn, B bf16 = wvT)
  gemm_k<float, bf16, 0, false, false, true><<<dim3(8, 16, 8), blk, 0, stream>>>(
      outAttn, wvT, nullptr, nullptr, ctx, 2048, 1024, 2048,
      (long)2048 * 2048, (long)1024 * 2048, (long)2048 * 1024, 0, 1.0f);
  // 9. g = gelu(ctx @ Wo + bo)  (A=ctx bf16, B=Wot bf16, bias per-n, gelu, out f32)
  gemm_k<bf16, bf16, 1, false, true, false><<<dim3(8, 128, 1), blk, 0, stream>>>(
      ctx, Wot, bo, nullptr, g, 16384, 1024, 1024, 0, 0, 0, 0, 1.0f);
  // 10. LayerNorm -> context output
  ln_k<<<dim3(16384), blk, 0, stream>>>(g, gamma, beta, outCtx);
}

// Round 2
// 682.382 us; speedup vs baseline: 1.1813x; 1.1813x over previous
//
#include <hip/hip_runtime.h>
#include <math.h>

typedef __bf16 bf16;
typedef __bf16 bf16x8 __attribute__((ext_vector_type(8)));
typedef __bf16 bf16x4 __attribute__((ext_vector_type(4)));
typedef float f32x4 __attribute__((ext_vector_type(4)));

// ---- async global->LDS, 16B per lane. LDS dest must be wave-uniform base (+lane*16 implicit).
__device__ inline void gload16(const void* g, void* l) {
  typedef __attribute__((address_space(1))) const unsigned int guint;
  typedef __attribute__((address_space(3))) unsigned int luint;
  __builtin_amdgcn_global_load_lds((guint*)g, (luint*)l, 16, 0, 0);
}

// ---------------- all-bf16 GEMM, m97 structure: 128x128 tile, BK=32, 4 waves,
// global_load_lds staging, linear LDS [128][32], mfma 16x16x32 bf16.
// C[m][n] = op( scale * sum_k A[m][k]*B[n][k] + bias +/- mask )
// BIAS_MODE: 0 none, 1 per-col(n), 2 per-row(m). MASK adds -1e9*mT[m][n].
template<int BIAS_MODE, bool MASK, bool GELU, bool OUT_BF16>
__global__ __launch_bounds__(256)
void bgemm_k(const bf16* __restrict__ A, const bf16* __restrict__ B,
             const float* __restrict__ bias, const signed char* __restrict__ mT,
             void* __restrict__ Cout, int N, int K,
             long sAb, long sBb, long sCb, long sMb, float scale)
{
  __shared__ bf16 As[128 * 32];
  __shared__ bf16 Bs[128 * 32];
  const int t    = threadIdx.x;
  const int zb   = blockIdx.z;
  const int gx   = gridDim.x;
  // XCD-aware bijective swizzle (nwg % 8 == 0 for all our grids)
  const int nwg  = gx * gridDim.y;
  const int orig = blockIdx.y * gx + blockIdx.x;
  const int swz  = (orig & 7) * (nwg >> 3) + (orig >> 3);
  const int m0   = (swz / gx) * 128;
  const int n0   = (swz % gx) * 128;

  const int wave = t >> 6;
  const int lane = t & 63;

  // staging: wave w stages rows [w*32, w*32+32), 2 issues of 16 rows each (A and B)
  const int sr = lane >> 2;          // row within 16-row group
  const int sc = (lane & 3) * 8;     // bf16 element col (16B granules)
  const bf16* Ag0 = A + (size_t)zb * sAb + (size_t)(wave * 32 + sr) * K + sc;
  const bf16* Ag1 = Ag0 + (size_t)16 * K;
  const bf16* Bg0 = B + (size_t)zb * sBb + (size_t)(wave * 32 + sr) * K + sc;
  const bf16* Bg1 = Bg0 + (size_t)16 * K;
  bf16* Al0 = &As[(wave * 32 + 0) * 32];
  bf16* Al1 = &As[(wave * 32 + 16) * 32];
  bf16* Bl0 = &Bs[(wave * 32 + 0) * 32];
  bf16* Bl1 = &Bs[(wave * 32 + 16) * 32];
  const size_t mOffA = (size_t)m0 * K;
  const size_t mOffB = (size_t)n0 * K;

  // fragment indices
  const int wm = (wave >> 1) << 6;   // 0 or 64
  const int wn = (wave & 1) << 6;
  const int fr = lane & 15;
  const int fg = lane >> 4;          // 0..3 -> k-group of 8

  f32x4 acc[4][4] = {};

  for (int k0 = 0; k0 < K; k0 += 32) {
    gload16(Ag0 + mOffA + k0, Al0);
    gload16(Ag1 + mOffA + k0, Al1);
    gload16(Bg0 + mOffB + k0, Bl0);
    gload16(Bg1 + mOffB + k0, Bl1);
    __syncthreads();               // drains vmcnt -> LDS ready
    bf16x8 af[4], bfv[4];
#pragma unroll
    for (int i = 0; i < 4; ++i) af[i]  = *(const bf16x8*)&As[(wm + i * 16 + fr) * 32 + fg * 8];
#pragma unroll
    for (int i = 0; i < 4; ++i) bfv[i] = *(const bf16x8*)&Bs[(wn + i * 16 + fr) * 32 + fg * 8];
#pragma unroll
    for (int mi = 0; mi < 4; ++mi)
#pragma unroll
      for (int ni = 0; ni < 4; ++ni)
        acc[mi][ni] = __builtin_amdgcn_mfma_f32_16x16x32_bf16(af[mi], bfv[ni], acc[mi][ni], 0, 0, 0);
    __syncthreads();               // protect LDS from next-iter staging
  }

  const signed char* mb = mT + (size_t)zb * sMb;
#pragma unroll
  for (int mi = 0; mi < 4; ++mi) {
#pragma unroll
    for (int ni = 0; ni < 4; ++ni) {
      const int col = n0 + wn + ni * 16 + fr;
#pragma unroll
      for (int i = 0; i < 4; ++i) {
        const int r = m0 + wm + mi * 16 + fg * 4 + i;   // C/D: row=(lane>>4)*4+i, col=lane&15
        float v = acc[mi][ni][i] * scale;
        if constexpr (BIAS_MODE == 1) v += bias[col];
        if constexpr (BIAS_MODE == 2) v += bias[r];
        if constexpr (MASK) v += -1e9f * (float)mb[(size_t)r * N + col];
        if constexpr (GELU) v = 0.5f * v * (1.0f + erff(v * 0.70710678118f));
        const size_t off = (size_t)zb * sCb + (size_t)r * N + col;
        if constexpr (OUT_BF16) ((bf16*)Cout)[off] = (bf16)v;
        else                    ((float*)Cout)[off] = v;
      }
    }
  }
}

// ---------------- f32 -> bf16 bulk convert (8 elems/thread/iter)
__global__ __launch_bounds__(256)
void conv_k(const float* __restrict__ in, bf16* __restrict__ out, long n8)
{
  for (long i = blockIdx.x * 256 + threadIdx.x; i < n8; i += (long)gridDim.x * 256) {
    f32x4 a = *(const f32x4*)(in + i * 8);
    f32x4 b = *(const f32x4*)(in + i * 8 + 4);
    bf16x8 o;
#pragma unroll
    for (int j = 0; j < 4; ++j) { o[j] = (bf16)a[j]; o[4 + j] = (bf16)b[j]; }
    *(bf16x8*)(out + i * 8) = o;
  }
}

// ---------------- weight transpose+convert: out[n][k] = (bf16)W[k][n], 1024x1024, z selects weight
__global__ __launch_bounds__(256)
void wtrans_k(const float* __restrict__ W0, const float* __restrict__ W1,
              const float* __restrict__ W2, const float* __restrict__ W3,
              bf16* __restrict__ out)
{
  const float* Ws[4] = {W0, W1, W2, W3};
  const float* W = Ws[blockIdx.z];
  bf16* o = out + (size_t)blockIdx.z * (1024 * 1024);
  __shared__ bf16 tile[64][72];
  const int t  = threadIdx.x;
  const int c0 = blockIdx.x * 64;
  const int r0 = blockIdx.y * 64;
  {
    const int rr = t >> 2;
    const int cc = (t & 3) * 16;
    const float* src = W + (size_t)(r0 + rr) * 1024 + c0 + cc;
#pragma unroll
    for (int j = 0; j < 16; j += 4) {
      f32x4 v = *(const f32x4*)(src + j);
#pragma unroll
      for (int i = 0; i < 4; ++i) tile[cc + j + i][rr] = (bf16)v[i];
    }
  }
  __syncthreads();
  {
    const int nr = t >> 2;
    const int kc = (t & 3) * 16;
    bf16* dst = o + (size_t)(c0 + nr) * 1024 + r0 + kc;
    *(bf16x8*)dst       = *(const bf16x8*)&tile[nr][kc];
    *(bf16x8*)(dst + 8) = *(const bf16x8*)&tile[nr][kc + 8];
  }
}

// ---------------- mask transpose: maskT[b][k][q] = (int8)mask[b][q][k]
__global__ __launch_bounds__(256)
void maskT_k(const int* __restrict__ mask, signed char* __restrict__ mT)
{
  __shared__ signed char tile[64][65];
  const int t  = threadIdx.x;
  const int b  = blockIdx.z;
  const int k0 = blockIdx.x * 64;
  const int q0 = blockIdx.y * 64;
  {
    const int iq = t >> 2;
    const int ic = (t & 3) * 16;
    const int* src = mask + ((size_t)b * 2048 + q0 + iq) * 2048 + k0 + ic;
#pragma unroll
    for (int j = 0; j < 16; j += 4) {
      int4 v = *(const int4*)(src + j);
      tile[ic + j + 0][iq] = (signed char)v.x;
      tile[ic + j + 1][iq] = (signed char)v.y;
      tile[ic + j + 2][iq] = (signed char)v.z;
      tile[ic + j + 3][iq] = (signed char)v.w;
    }
  }
  __syncthreads();
  {
    const int ik = t >> 2;
    const int iq = (t & 3) * 16;
    signed char* dst = mT + ((size_t)b * 2048 + k0 + ik) * 2048 + q0 + iq;
#pragma unroll
    for (int j = 0; j < 16; ++j) dst[j] = tile[ik][iq + j];
  }
}

// ---------------- in-place row softmax over 2048 cols + bf16 copy
__global__ __launch_bounds__(256)
void softmax_rows_k(float* __restrict__ P, bf16* __restrict__ Pb)
{
  float* p = P + (size_t)blockIdx.x * 2048;
  bf16*  pb = Pb + (size_t)blockIdx.x * 2048;
  const int t = threadIdx.x;
  const int wave = t >> 6, lane = t & 63;
  f32x4 v0 = *(const f32x4*)(p + t * 4);
  f32x4 v1 = *(const f32x4*)(p + 1024 + t * 4);
  float m = -3e38f;
#pragma unroll
  for (int j = 0; j < 4; ++j) { m = fmaxf(m, v0[j]); m = fmaxf(m, v1[j]); }
#pragma unroll
  for (int off = 32; off; off >>= 1) m = fmaxf(m, __shfl_xor(m, off));
  __shared__ float red[8];
  if (lane == 0) red[wave] = m;
  __syncthreads();
  m = fmaxf(fmaxf(red[0], red[1]), fmaxf(red[2], red[3]));
  float s = 0.0f;
#pragma unroll
  for (int j = 0; j < 4; ++j) {
    v0[j] = __expf(v0[j] - m); s += v0[j];
    v1[j] = __expf(v1[j] - m); s += v1[j];
  }
#pragma unroll
  for (int off = 32; off; off >>= 1) s += __shfl_xor(s, off);
  if (lane == 0) red[4 + wave] = s;
  __syncthreads();
  s = red[4] + red[5] + red[6] + red[7];
  const float inv = 1.0f / s;
  bf16x4 b0, b1;
#pragma unroll
  for (int j = 0; j < 4; ++j) {
    v0[j] *= inv; v1[j] *= inv;
    b0[j] = (bf16)v0[j]; b1[j] = (bf16)v1[j];
  }
  *(f32x4*)(p + t * 4)        = v0;
  *(f32x4*)(p + 1024 + t * 4) = v1;
  *(bf16x4*)(pb + t * 4)        = b0;
  *(bf16x4*)(pb + 1024 + t * 4) = b1;
}

// ---------------- LayerNorm over 1024 (one block per row)
__global__ __launch_bounds__(256)
void ln_k(const float* __restrict__ g, const float* __restrict__ gamma,
          const float* __restrict__ beta, float* __restrict__ out)
{
  const float* p = g + (size_t)blockIdx.x * 1024;
  const int t = threadIdx.x;
  const int wave = t >> 6, lane = t & 63;
  f32x4 v = *(const f32x4*)(p + t * 4);
  float s = v[0] + v[1] + v[2] + v[3];
  float q = v[0]*v[0] + v[1]*v[1] + v[2]*v[2] + v[3]*v[3];
#pragma unroll
  for (int off = 32; off; off >>= 1) { s += __shfl_xor(s, off); q += __shfl_xor(q, off); }
  __shared__ float red[16];
  if (lane == 0) { red[wave] = s; red[8 + wave] = q; }
  __syncthreads();
  s = red[0] + red[1] + red[2] + red[3];
  q = red[8] + red[9] + red[10] + red[11];
  const float mu   = s * (1.0f / 1024.0f);
  const float var  = q * (1.0f / 1024.0f) - mu * mu;
  const float rstd = rsqrtf(var + 1e-5f);
  f32x4 gm = *(const f32x4*)(gamma + t * 4);
  f32x4 bt = *(const f32x4*)(beta + t * 4);
  f32x4 o;
#pragma unroll
  for (int j = 0; j < 4; ++j) o[j] = (v[j] - mu) * rstd * gm[j] + bt[j];
  *(f32x4*)(out + (size_t)blockIdx.x * 1024 + t * 4) = o;
}

extern "C" void kernel_launch(void* const* d_in, const int* in_sizes, int n_in,
                              void* d_out, int out_size, void* d_ws, size_t ws_size,
                              hipStream_t stream)
{
  const float* Q     = (const float*)d_in[0];
  const float* Kin   = (const float*)d_in[1];
  const float* V     = (const float*)d_in[2];
  const int*   mask  = (const int*)d_in[3];
  const float* Wq    = (const float*)d_in[4];
  const float* bq    = (const float*)d_in[5];
  const float* Wk    = (const float*)d_in[6];
  const float* bk    = (const float*)d_in[7];
  const float* Wv    = (const float*)d_in[8];
  const float* bv    = (const float*)d_in[9];
  const float* Wo    = (const float*)d_in[10];
  const float* bo    = (const float*)d_in[11];
  const float* gamma = (const float*)d_in[12];
  const float* beta  = (const float*)d_in[13];

  float* outCtx  = (float*)d_out;                      // [8,2048,1024]
  float* outAttn = outCtx + (size_t)8 * 2048 * 1024;   // [8,2048,2048] (k,q)

  // workspace (MiB offsets), peak 136 MiB:
  // wts   [0,8)      4x bf16 1024x1024 transposed weights        (whole run)
  // qp    [8,40)     bf16 [16384][1024]   -> dead after QKT; wvT reuses
  // kp    [40,72)    bf16 [16384][1024]   -> dead after QKT; attnb reuses
  // Qb    [72,104)   bf16                 -> dead after qp;  maskT reuses
  // Kb    [104,136)  bf16                 -> dead after kp;  Vb, then ctx reuse
  // maskT [72,104)   int8 [8][2048][2048] -> dead after QKT; attnb reuses
  // attnb [40,104)   bf16 [8][2048][2048] -> dead after PV;  g reuses
  // wvT   [8,40)     bf16 [8][1024][2048]
  // Vb    [104,136)  bf16                 -> dead after wvT
  // ctx   [104,136)  bf16 [16384][1024]
  // g     [40,104)   f32  [16384][1024]
  char* ws = (char*)d_ws;
  const size_t MB = 1048576;
  bf16*        wts   = (bf16*)(ws + 0 * MB);
  bf16*        qp    = (bf16*)(ws + 8 * MB);
  bf16*        kp    = (bf16*)(ws + 40 * MB);
  bf16*        Qb    = (bf16*)(ws + 72 * MB);
  bf16*        Kb    = (bf16*)(ws + 104 * MB);
  signed char* mT    = (signed char*)(ws + 72 * MB);
  bf16*        attnb = (bf16*)(ws + 40 * MB);
  bf16*        wvT   = (bf16*)(ws + 8 * MB);
  bf16*        Vb    = (bf16*)(ws + 104 * MB);
  bf16*        ctx   = (bf16*)(ws + 104 * MB);
  float*       g     = (float*)(ws + 40 * MB);
  bf16* Wqt = wts;
  bf16* Wkt = wts + 1 * 1024 * 1024;
  bf16* Wvt = wts + 2 * 1024 * 1024;
  bf16* Wot = wts + 3 * 1024 * 1024;

  const dim3 blk(256);
  const long n8 = (long)16384 * 1024 / 8;

  // 1. weights -> bf16 transposed
  wtrans_k<<<dim3(16, 16, 4), blk, 0, stream>>>(Wq, Wk, Wv, Wo, wts);
  // 2. Q,K -> bf16
  conv_k<<<dim3(2048), blk, 0, stream>>>(Q, Qb, n8);
  conv_k<<<dim3(2048), blk, 0, stream>>>(Kin, Kb, n8);
  // 3. qp = Qb @ Wqt + bq ; kp = Kb @ Wkt + bk
  bgemm_k<1, false, false, true><<<dim3(8, 128, 1), blk, 0, stream>>>(
      Qb, Wqt, bq, nullptr, qp, 1024, 1024, 0, 0, 0, 0, 1.0f);
  bgemm_k<1, false, false, true><<<dim3(8, 128, 1), blk, 0, stream>>>(
      Kb, Wkt, bk, nullptr, kp, 1024, 1024, 0, 0, 0, 0, 1.0f);
  // 4. V -> bf16 (into Kb slot, Kb now dead)
  conv_k<<<dim3(2048), blk, 0, stream>>>(V, Vb, n8);
  // 5. mask transpose (into Qb slot, Qb now dead)
  maskT_k<<<dim3(32, 32, 8), blk, 0, stream>>>(mask, mT);
  // 6. T[b][k][q] = kp[k]·qp[q]/32 - 1e9*maskT -> d_out attn (f32)
  bgemm_k<0, true, false, false><<<dim3(16, 16, 8), blk, 0, stream>>>(
      kp, qp, nullptr, mT, outAttn, 2048, 1024,
      (long)2048 * 1024, (long)2048 * 1024, (long)2048 * 2048, (long)2048 * 2048, 0.03125f);
  // 7. wvT[b][v][q] = Wvt @ Vb^T + bv (per-row)
  bgemm_k<2, false, false, true><<<dim3(16, 8, 8), blk, 0, stream>>>(
      Wvt, Vb, bv, nullptr, wvT, 2048, 1024,
      0, (long)2048 * 1024, (long)1024 * 2048, 0, 1.0f);
  // 8. softmax rows in place + bf16 copy
  softmax_rows_k<<<dim3(16384), blk, 0, stream>>>(outAttn, attnb);
  // 9. ctx[b][k][v] = sum_q attnb[k][q] * wvT[v][q]
  bgemm_k<0, false, false, true><<<dim3(8, 16, 8), blk, 0, stream>>>(
      attnb, wvT, nullptr, nullptr, ctx, 1024, 2048,
      (long)2048 * 2048, (long)1024 * 2048, (long)2048 * 1024, 0, 1.0f);
  // 10. g = gelu(ctx @ Wot + bo)
  bgemm_k<1, false, true, false><<<dim3(8, 128, 1), blk, 0, stream>>>(
      ctx, Wot, bo, nullptr, g, 1024, 1024, 0, 0, 0, 0, 1.0f);
  // 11. LayerNorm -> context output
  ln_k<<<dim3(16384), blk, 0, stream>>>(g, gamma, beta, outCtx);
}

// Round 3
// 534.213 us; speedup vs baseline: 1.5089x; 1.2774x over previous
//
#include <hip/hip_runtime.h>
#include <math.h>

typedef __bf16 bf16;
typedef __bf16 bf16x8 __attribute__((ext_vector_type(8)));
typedef __bf16 bf16x4 __attribute__((ext_vector_type(4)));
typedef float f32x4 __attribute__((ext_vector_type(4)));

// ---- async global->LDS, 16B per lane. LDS dest = wave-uniform base (+lane*16 implicit).
__device__ inline void gload16(const void* g, void* l) {
  typedef __attribute__((address_space(1))) const unsigned int guint;
  typedef __attribute__((address_space(3))) unsigned int luint;
  __builtin_amdgcn_global_load_lds((guint*)g, (luint*)l, 16, 0, 0);
}

// ================= 256x256 8-phase GEMM (T1 XCD-swizzle, T2 LDS swizzle,
// T3/T4 counted-vmcnt pipeline, T5 setprio). 512 threads = 8 waves (2Mx4N),
// per-wave output 128x64 (acc[8][4]), mfma 16x16x32 bf16.
// K is processed in 32-wide slabs s=0..K/32-1; LDS ring of 4 slots per operand
// (4 x 256x32 bf16 = 64 KB each for A and B = 128 KB total).
// Slab s is staged (A-part at half-slab H=2s, B-part H=2s+1) at phase P=H-5,
// first read at phase 2s; one vmcnt(2) per K-tile guarantees landing.
// LDS swizzle: 16B-granule g' = g ^ ((row>>1)&3) -> 2-way conflicts only.
// C[m][n] = op(scale * sum_k A[m][k]*B[n][k] + bias +/- mask)
template<int BIAS_MODE, bool MASK, bool GELU, bool OUT_BF16>
__global__ __launch_bounds__(512, 2)
void bgemm8_k(const bf16* __restrict__ A, const bf16* __restrict__ B,
              const float* __restrict__ bias, const signed char* __restrict__ mT,
              void* __restrict__ Cout, int N, int K,
              long sAb, long sBb, long sCb, long sMb, float scale)
{
  __shared__ bf16 As[4 * 8192];   // [slot][256][32]
  __shared__ bf16 Bs[4 * 8192];

  const int t    = threadIdx.x;
  const int zb   = blockIdx.z;
  const int gx   = gridDim.x;
  const int nwg  = gx * gridDim.y;
  const int orig = blockIdx.y * gx + blockIdx.x;
  const int swz  = (orig & 7) * (nwg >> 3) + (orig >> 3);   // nwg % 8 == 0 always here
  const int m0   = (swz / gx) * 256;
  const int n0   = (swz % gx) * 256;

  const int wave = t >> 6;
  const int lane = t & 63;
  const int wm = wave >> 2;          // 0..1 -> rows wm*128..+128
  const int wn = wave & 3;           // 0..3 -> cols wn*64..+64
  const int fr = lane & 15;
  const int fg = lane >> 4;          // 0..3

  // ---- staging constants (2 issues per thread per half-slab)
  const bf16* Abase = A + (size_t)zb * sAb + (size_t)m0 * K;
  const bf16* Bbase = B + (size_t)zb * sBb + (size_t)n0 * K;
  size_t gOff[2];
  int    ldsOff[2];
#pragma unroll
  for (int j = 0; j < 2; ++j) {
    const int L   = j * 8192 + t * 16;   // byte offset within 16KB slab-part
    const int row = L >> 6;              // 0..255
    const int gp  = (L >> 4) & 3;        // linear LDS granule
    const int g   = gp ^ ((row >> 1) & 3);   // pre-swizzled global granule
    gOff[j]   = (size_t)row * K + (size_t)g * 8;
    ldsOff[j] = j * 4096 + wave * 512;   // wave-uniform; HW adds lane*16B
  }
  const int HMAX = (K >> 5) * 2;   // 2 half-slabs per 32-wide slab

  auto stage = [&](int H) {
    if (H >= HMAX) return;
    const int s    = H >> 1;
    const int slot = s & 3;
    const size_t kof = (size_t)s * 32;
    if ((H & 1) == 0) {
      gload16(Abase + kof + gOff[0], As + slot * 8192 + ldsOff[0]);
      gload16(Abase + kof + gOff[1], As + slot * 8192 + ldsOff[1]);
    } else {
      gload16(Bbase + kof + gOff[0], Bs + slot * 8192 + ldsOff[0]);
      gload16(Bbase + kof + gOff[1], Bs + slot * 8192 + ldsOff[1]);
    }
  };

  // ---- fragment read offsets (swizzled): row base multiple of 16 -> xor is (fr>>1)&3
  const int xsw  = (fg ^ ((fr >> 1) & 3)) * 8;
  const int aoff = (wm * 128 + fr) * 32 + xsw;
  const int boff = (wn * 64 + fr) * 32 + xsw;

  f32x4 acc[8][4] = {};
  const int T = K >> 6;   // K-tiles of 64

  // prologue: A(s0),B(s0),A(s1),B(s1),A(s2); slabs 0,1 landed after vmcnt(2)
  stage(0); stage(1); stage(2); stage(3); stage(4);
  asm volatile("s_waitcnt vmcnt(2)" ::: "memory");
  asm volatile("s_barrier" ::: "memory");

  for (int tt = 0; tt < T; ++tt) {
#pragma unroll
    for (int p = 0; p < 4; ++p) {
      const int kk   = p & 1;        // k-half of this K-tile (32-slab)
      const int oh   = p >> 1;       // output half (mi 0-3 / 4-7)
      const int slot = (2 * tt + kk) & 3;
      bf16x8 af[4], bfv[4];
#pragma unroll
      for (int i = 0; i < 4; ++i)
        af[i]  = *(const bf16x8*)(As + slot * 8192 + aoff + (oh * 4 + i) * 512);
#pragma unroll
      for (int i = 0; i < 4; ++i)
        bfv[i] = *(const bf16x8*)(Bs + slot * 8192 + boff + i * 512);
      stage(4 * tt + p + 5);         // one half-slab, ~5 phases ahead of first use
      asm volatile("s_barrier" ::: "memory");
      __builtin_amdgcn_s_setprio(1);
#pragma unroll
      for (int mi = 0; mi < 4; ++mi)
#pragma unroll
        for (int ni = 0; ni < 4; ++ni)
          acc[oh * 4 + mi][ni] =
            __builtin_amdgcn_mfma_f32_16x16x32_bf16(af[mi], bfv[ni], acc[oh * 4 + mi][ni], 0, 0, 0);
      __builtin_amdgcn_s_setprio(0);
      if (p == 3) {
        // protect tile tt+1's slabs (staged >=4 phases ago); drain fully near the end
        if (tt >= T - 2) asm volatile("s_waitcnt vmcnt(0)" ::: "memory");
        else             asm volatile("s_waitcnt vmcnt(2)" ::: "memory");
      }
      asm volatile("s_barrier" ::: "memory");
    }
  }

  const signed char* mb = mT + (size_t)zb * sMb;
#pragma unroll
  for (int mi = 0; mi < 8; ++mi) {
#pragma unroll
    for (int ni = 0; ni < 4; ++ni) {
      const int col = n0 + wn * 64 + ni * 16 + fr;
#pragma unroll
      for (int i = 0; i < 4; ++i) {
        const int r = m0 + wm * 128 + mi * 16 + fg * 4 + i;  // C/D: row=(lane>>4)*4+i, col=lane&15
        float v = acc[mi][ni][i] * scale;
        if constexpr (BIAS_MODE == 1) v += bias[col];
        if constexpr (BIAS_MODE == 2) v += bias[r];
        if constexpr (MASK) v += -1e9f * (float)mb[(size_t)r * N + col];
        if constexpr (GELU) v = 0.5f * v * (1.0f + erff(v * 0.70710678118f));
        const size_t off = (size_t)zb * sCb + (size_t)r * N + col;
        if constexpr (OUT_BF16) ((bf16*)Cout)[off] = (bf16)v;
        else                    ((float*)Cout)[off] = v;
      }
    }
  }
}

// ---------------- f32 -> bf16 bulk convert (8 elems/thread/iter)
__global__ __launch_bounds__(256)
void conv_k(const float* __restrict__ in, bf16* __restrict__ out, long n8)
{
  for (long i = blockIdx.x * 256 + threadIdx.x; i < n8; i += (long)gridDim.x * 256) {
    f32x4 a = *(const f32x4*)(in + i * 8);
    f32x4 b = *(const f32x4*)(in + i * 8 + 4);
    bf16x8 o;
#pragma unroll
    for (int j = 0; j < 4; ++j) { o[j] = (bf16)a[j]; o[4 + j] = (bf16)b[j]; }
    *(bf16x8*)(out + i * 8) = o;
  }
}

// ---------------- weight transpose+convert: out[n][k] = (bf16)W[k][n], 1024x1024, z selects weight
__global__ __launch_bounds__(256)
void wtrans_k(const float* __restrict__ W0, const float* __restrict__ W1,
              const float* __restrict__ W2, const float* __restrict__ W3,
              bf16* __restrict__ out)
{
  const float* Ws[4] = {W0, W1, W2, W3};
  const float* W = Ws[blockIdx.z];
  bf16* o = out + (size_t)blockIdx.z * (1024 * 1024);
  __shared__ bf16 tile[64][72];
  const int t  = threadIdx.x;
  const int c0 = blockIdx.x * 64;
  const int r0 = blockIdx.y * 64;
  {
    const int rr = t >> 2;
    const int cc = (t & 3) * 16;
    const float* src = W + (size_t)(r0 + rr) * 1024 + c0 + cc;
#pragma unroll
    for (int j = 0; j < 16; j += 4) {
      f32x4 v = *(const f32x4*)(src + j);
#pragma unroll
      for (int i = 0; i < 4; ++i) tile[cc + j + i][rr] = (bf16)v[i];
    }
  }
  __syncthreads();
  {
    const int nr = t >> 2;
    const int kc = (t & 3) * 16;
    bf16* dst = o + (size_t)(c0 + nr) * 1024 + r0 + kc;
    *(bf16x8*)dst       = *(const bf16x8*)&tile[nr][kc];
    *(bf16x8*)(dst + 8) = *(const bf16x8*)&tile[nr][kc + 8];
  }
}

// ---------------- mask transpose: maskT[b][k][q] = (int8)mask[b][q][k]
__global__ __launch_bounds__(256)
void maskT_k(const int* __restrict__ mask, signed char* __restrict__ mT)
{
  __shared__ signed char tile[64][65];
  const int t  = threadIdx.x;
  const int b  = blockIdx.z;
  const int k0 = blockIdx.x * 64;
  const int q0 = blockIdx.y * 64;
  {
    const int iq = t >> 2;
    const int ic = (t & 3) * 16;
    const int* src = mask + ((size_t)b * 2048 + q0 + iq) * 2048 + k0 + ic;
#pragma unroll
    for (int j = 0; j < 16; j += 4) {
      int4 v = *(const int4*)(src + j);
      tile[ic + j + 0][iq] = (signed char)v.x;
      tile[ic + j + 1][iq] = (signed char)v.y;
      tile[ic + j + 2][iq] = (signed char)v.z;
      tile[ic + j + 3][iq] = (signed char)v.w;
    }
  }
  __syncthreads();
  {
    const int ik = t >> 2;
    const int iq = (t & 3) * 16;
    signed char* dst = mT + ((size_t)b * 2048 + k0 + ik) * 2048 + q0 + iq;
#pragma unroll
    for (int j = 0; j < 16; ++j) dst[j] = tile[ik][iq + j];
  }
}

// ---------------- in-place row softmax over 2048 cols + bf16 copy
__global__ __launch_bounds__(256)
void softmax_rows_k(float* __restrict__ P, bf16* __restrict__ Pb)
{
  float* p = P + (size_t)blockIdx.x * 2048;
  bf16*  pb = Pb + (size_t)blockIdx.x * 2048;
  const int t = threadIdx.x;
  const int wave = t >> 6, lane = t & 63;
  f32x4 v0 = *(const f32x4*)(p + t * 4);
  f32x4 v1 = *(const f32x4*)(p + 1024 + t * 4);
  float m = -3e38f;
#pragma unroll
  for (int j = 0; j < 4; ++j) { m = fmaxf(m, v0[j]); m = fmaxf(m, v1[j]); }
#pragma unroll
  for (int off = 32; off; off >>= 1) m = fmaxf(m, __shfl_xor(m, off));
  __shared__ float red[8];
  if (lane == 0) red[wave] = m;
  __syncthreads();
  m = fmaxf(fmaxf(red[0], red[1]), fmaxf(red[2], red[3]));
  float s = 0.0f;
#pragma unroll
  for (int j = 0; j < 4; ++j) {
    v0[j] = __expf(v0[j] - m); s += v0[j];
    v1[j] = __expf(v1[j] - m); s += v1[j];
  }
#pragma unroll
  for (int off = 32; off; off >>= 1) s += __shfl_xor(s, off);
  if (lane == 0) red[4 + wave] = s;
  __syncthreads();
  s = red[4] + red[5] + red[6] + red[7];
  const float inv = 1.0f / s;
  bf16x4 b0, b1;
#pragma unroll
  for (int j = 0; j < 4; ++j) {
    v0[j] *= inv; v1[j] *= inv;
    b0[j] = (bf16)v0[j]; b1[j] = (bf16)v1[j];
  }
  *(f32x4*)(p + t * 4)        = v0;
  *(f32x4*)(p + 1024 + t * 4) = v1;
  *(bf16x4*)(pb + t * 4)        = b0;
  *(bf16x4*)(pb + 1024 + t * 4) = b1;
}

// ---------------- LayerNorm over 1024 (one block per row)
__global__ __launch_bounds__(256)
void ln_k(const float* __restrict__ g, const float* __restrict__ gamma,
          const float* __restrict__ beta, float* __restrict__ out)
{
  const float* p = g + (size_t)blockIdx.x * 1024;
  const int t = threadIdx.x;
  const int wave = t >> 6, lane = t & 63;
  f32x4 v = *(const f32x4*)(p + t * 4);
  float s = v[0] + v[1] + v[2] + v[3];
  float q = v[0]*v[0] + v[1]*v[1] + v[2]*v[2] + v[3]*v[3];
#pragma unroll
  for (int off = 32; off; off >>= 1) { s += __shfl_xor(s, off); q += __shfl_xor(q, off); }
  __shared__ float red[16];
  if (lane == 0) { red[wave] = s; red[8 + wave] = q; }
  __syncthreads();
  s = red[0] + red[1] + red[2] + red[3];
  q = red[8] + red[9] + red[10] + red[11];
  const float mu   = s * (1.0f / 1024.0f);
  const float var  = q * (1.0f / 1024.0f) - mu * mu;
  const float rstd = rsqrtf(var + 1e-5f);
  f32x4 gm = *(const f32x4*)(gamma + t * 4);
  f32x4 bt = *(const f32x4*)(beta + t * 4);
  f32x4 o;
#pragma unroll
  for (int j = 0; j < 4; ++j) o[j] = (v[j] - mu) * rstd * gm[j] + bt[j];
  *(f32x4*)(out + (size_t)blockIdx.x * 1024 + t * 4) = o;
}

extern "C" void kernel_launch(void* const* d_in, const int* in_sizes, int n_in,
                              void* d_out, int out_size, void* d_ws, size_t ws_size,
                              hipStream_t stream)
{
  const float* Q     = (const float*)d_in[0];
  const float* Kin   = (const float*)d_in[1];
  const float* V     = (const float*)d_in[2];
  const int*   mask  = (const int*)d_in[3];
  const float* Wq    = (const float*)d_in[4];
  const float* bq    = (const float*)d_in[5];
  const float* Wk    = (const float*)d_in[6];
  const float* bk    = (const float*)d_in[7];
  const float* Wv    = (const float*)d_in[8];
  const float* bv    = (const float*)d_in[9];
  const float* Wo    = (const float*)d_in[10];
  const float* bo    = (const float*)d_in[11];
  const float* gamma = (const float*)d_in[12];
  const float* beta  = (const float*)d_in[13];

  float* outCtx  = (float*)d_out;                      // [8,2048,1024]
  float* outAttn = outCtx + (size_t)8 * 2048 * 1024;   // [8,2048,2048] (k,q)

  // workspace (MiB offsets), peak 136 MiB — same layout as round 2:
  char* ws = (char*)d_ws;
  const size_t MB = 1048576;
  bf16*        wts   = (bf16*)(ws + 0 * MB);
  bf16*        qp    = (bf16*)(ws + 8 * MB);
  bf16*        kp    = (bf16*)(ws + 40 * MB);
  bf16*        Qb    = (bf16*)(ws + 72 * MB);
  bf16*        Kb    = (bf16*)(ws + 104 * MB);
  signed char* mT    = (signed char*)(ws + 72 * MB);
  bf16*        attnb = (bf16*)(ws + 40 * MB);
  bf16*        wvT   = (bf16*)(ws + 8 * MB);
  bf16*        Vb    = (bf16*)(ws + 104 * MB);
  bf16*        ctx   = (bf16*)(ws + 104 * MB);
  float*       g     = (float*)(ws + 40 * MB);
  bf16* Wqt = wts;
  bf16* Wkt = wts + 1 * 1024 * 1024;
  bf16* Wvt = wts + 2 * 1024 * 1024;
  bf16* Wot = wts + 3 * 1024 * 1024;

  const dim3 blk(256);
  const dim3 blk8(512);
  const long n8 = (long)16384 * 1024 / 8;

  // 1. weights -> bf16 transposed
  wtrans_k<<<dim3(16, 16, 4), blk, 0, stream>>>(Wq, Wk, Wv, Wo, wts);
  // 2. Q,K -> bf16
  conv_k<<<dim3(2048), blk, 0, stream>>>(Q, Qb, n8);
  conv_k<<<dim3(2048), blk, 0, stream>>>(Kin, Kb, n8);
  // 3. qp = Qb @ Wqt + bq ; kp = Kb @ Wkt + bk
  bgemm8_k<1, false, false, true><<<dim3(4, 64, 1), blk8, 0, stream>>>(
      Qb, Wqt, bq, nullptr, qp, 1024, 1024, 0, 0, 0, 0, 1.0f);
  bgemm8_k<1, false, false, true><<<dim3(4, 64, 1), blk8, 0, stream>>>(
      Kb, Wkt, bk, nullptr, kp, 1024, 1024, 0, 0, 0, 0, 1.0f);
  // 4. V -> bf16 (into Kb slot, Kb now dead)
  conv_k<<<dim3(2048), blk, 0, stream>>>(V, Vb, n8);
  // 5. mask transpose (into Qb slot, Qb now dead)
  maskT_k<<<dim3(32, 32, 8), blk, 0, stream>>>(mask, mT);
  // 6. T[b][k][q] = kp[k]·qp[q]/32 - 1e9*maskT -> d_out attn (f32)
  bgemm8_k<0, true, false, false><<<dim3(8, 8, 8), blk8, 0, stream>>>(
      kp, qp, nullptr, mT, outAttn, 2048, 1024,
      (long)2048 * 1024, (long)2048 * 1024, (long)2048 * 2048, (long)2048 * 2048, 0.03125f);
  // 7. wvT[b][v][q] = Wvt @ Vb^T + bv (per-row)
  bgemm8_k<2, false, false, true><<<dim3(8, 4, 8), blk8, 0, stream>>>(
      Wvt, Vb, bv, nullptr, wvT, 2048, 1024,
      0, (long)2048 * 1024, (long)1024 * 2048, 0, 1.0f);
  // 8. softmax rows in place + bf16 copy
  softmax_rows_k<<<dim3(16384), blk, 0, stream>>>(outAttn, attnb);
  // 9. ctx[b][k][v] = sum_q attnb[k][q] * wvT[v][q]
  bgemm8_k<0, false, false, true><<<dim3(4, 8, 8), blk8, 0, stream>>>(
      attnb, wvT, nullptr, nullptr, ctx, 1024, 2048,
      (long)2048 * 2048, (long)1024 * 2048, (long)2048 * 1024, 0, 1.0f);
  // 10. g = gelu(ctx @ Wot + bo)
  bgemm8_k<1, false, true, false><<<dim3(4, 64, 1), blk8, 0, stream>>>(
      ctx, Wot, bo, nullptr, g, 1024, 1024, 0, 0, 0, 0, 1.0f);
  // 11. LayerNorm -> context output
  ln_k<<<dim3(16384), blk, 0, stream>>>(g, gamma, beta, outCtx);
}

// Round 4
// 505.857 us; speedup vs baseline: 1.5935x; 1.0561x over previous
//
#include <hip/hip_runtime.h>
#include <math.h>

typedef __bf16 bf16;
typedef __bf16 bf16x8 __attribute__((ext_vector_type(8)));
typedef __bf16 bf16x4 __attribute__((ext_vector_type(4)));
typedef float f32x4 __attribute__((ext_vector_type(4)));

// ---- async global->LDS, 16B per lane. LDS dest = wave-uniform base (+lane*16 implicit).
__device__ inline void gload16(const void* g, void* l) {
  typedef __attribute__((address_space(1))) const unsigned int guint;
  typedef __attribute__((address_space(3))) unsigned int luint;
  __builtin_amdgcn_global_load_lds((guint*)g, (luint*)l, 16, 0, 0);
}

// ================= 256x256 8-phase GEMM (T1 XCD-swizzle, T2 LDS swizzle,
// T3/T4 counted-vmcnt pipeline, T5 setprio). 512 threads = 8 waves (2Mx4N),
// per-wave output 128x64 (acc[8][4]), mfma 16x16x32 bf16.
// LDS ring of 4 slots per operand (4 x 256x32 bf16 = 64KB each).
// Slab s staged at half-slabs H=2s (A), 2s+1 (B); stage(H) issued at phase H-5.
// Waits (ring-4, in-order vmcnt, counts = 2 loads per half-slab):
//   p0-end: need slab 2tt+1 (H<=4tt+3); issued<=4tt+5 -> vmcnt(4)   [vmcnt(0) last tile]
//   p3-end: need slab 2tt+2 (H<=4tt+5); issued<=4tt+8 -> vmcnt(6)   [4 at T-2, none at T-1]
// LDS swizzle: 16B-granule g' = g ^ ((row>>1)&3) -> 2-way conflicts only.
// C[m][n] = op(scale * sum_k A[m][k]*B[n][k] + bias +/- mask); C row stride = ldc.
template<int BIAS_MODE, bool MASK, bool GELU, bool OUT_BF16>
__global__ __launch_bounds__(512, 2)
void bgemm8_k(const bf16* __restrict__ A, const bf16* __restrict__ B,
              const float* __restrict__ bias, const signed char* __restrict__ mT,
              void* __restrict__ Cout, int N, int ldc, int K,
              long sAb, long sBb, long sCb, long sMb, float scale)
{
  __shared__ bf16 As[4 * 8192];   // [slot][256][32]
  __shared__ bf16 Bs[4 * 8192];

  const int t    = threadIdx.x;
  const int zb   = blockIdx.z;
  const int gx   = gridDim.x;
  const int nwg  = gx * gridDim.y;
  const int orig = blockIdx.y * gx + blockIdx.x;
  const int swz  = (orig & 7) * (nwg >> 3) + (orig >> 3);   // nwg % 8 == 0 always here
  const int m0   = (swz / gx) * 256;
  const int n0   = (swz % gx) * 256;

  const int wave = t >> 6;
  const int lane = t & 63;
  const int wm = wave >> 2;          // 0..1 -> rows wm*128..+128
  const int wn = wave & 3;           // 0..3 -> cols wn*64..+64
  const int fr = lane & 15;
  const int fg = lane >> 4;          // 0..3

  // ---- staging constants (2 issues per thread per half-slab)
  const bf16* Abase = A + (size_t)zb * sAb + (size_t)m0 * K;
  const bf16* Bbase = B + (size_t)zb * sBb + (size_t)n0 * K;
  size_t gOff[2];
  int    ldsOff[2];
#pragma unroll
  for (int j = 0; j < 2; ++j) {
    const int L   = j * 8192 + t * 16;   // byte offset within 16KB slab-part
    const int row = L >> 6;              // 0..255
    const int gp  = (L >> 4) & 3;        // linear LDS granule
    const int g   = gp ^ ((row >> 1) & 3);   // pre-swizzled global granule
    gOff[j]   = (size_t)row * K + (size_t)g * 8;
    ldsOff[j] = j * 4096 + wave * 512;   // wave-uniform; HW adds lane*16B
  }
  const int HMAX = (K >> 5) * 2;   // 2 half-slabs per 32-wide slab

  auto stage = [&](int H) {
    if (H >= HMAX) return;
    const int s    = H >> 1;
    const int slot = s & 3;
    const size_t kof = (size_t)s * 32;
    if ((H & 1) == 0) {
      gload16(Abase + kof + gOff[0], As + slot * 8192 + ldsOff[0]);
      gload16(Abase + kof + gOff[1], As + slot * 8192 + ldsOff[1]);
    } else {
      gload16(Bbase + kof + gOff[0], Bs + slot * 8192 + ldsOff[0]);
      gload16(Bbase + kof + gOff[1], Bs + slot * 8192 + ldsOff[1]);
    }
  };

  // ---- fragment read offsets (swizzled): row base multiple of 16 -> xor is (fr>>1)&3
  const int xsw  = (fg ^ ((fr >> 1) & 3)) * 8;
  const int aoff = (wm * 128 + fr) * 32 + xsw;
  const int boff = (wn * 64 + fr) * 32 + xsw;

  f32x4 acc[8][4] = {};
  const int T = K >> 6;   // K-tiles of 64

  // prologue: A(s0),B(s0),A(s1),B(s1),A(s2); need slab 0 (H<=1) -> vmcnt(6)
  stage(0); stage(1); stage(2); stage(3); stage(4);
  asm volatile("s_waitcnt vmcnt(6)" ::: "memory");
  __builtin_amdgcn_s_barrier();

  for (int tt = 0; tt < T; ++tt) {
#pragma unroll
    for (int p = 0; p < 4; ++p) {
      const int kk   = p & 1;        // k-half of this K-tile (32-slab)
      const int oh   = p >> 1;       // output half (mi 0-3 / 4-7)
      const int slot = (2 * tt + kk) & 3;
      bf16x8 af[4], bfv[4];
#pragma unroll
      for (int i = 0; i < 4; ++i)
        af[i]  = *(const bf16x8*)(As + slot * 8192 + aoff + (oh * 4 + i) * 512);
#pragma unroll
      for (int i = 0; i < 4; ++i)
        bfv[i] = *(const bf16x8*)(Bs + slot * 8192 + boff + i * 512);
      stage(4 * tt + p + 5);         // one half-slab, 5 phases ahead of first use
      __builtin_amdgcn_s_barrier();
      __builtin_amdgcn_s_setprio(1);
#pragma unroll
      for (int mi = 0; mi < 4; ++mi)
#pragma unroll
        for (int ni = 0; ni < 4; ++ni)
          acc[oh * 4 + mi][ni] =
            __builtin_amdgcn_mfma_f32_16x16x32_bf16(af[mi], bfv[ni], acc[oh * 4 + mi][ni], 0, 0, 0);
      __builtin_amdgcn_s_setprio(0);
      if (p == 0) {                   // publish slab 2tt+1 for p1 reads (wait THEN barrier)
        if (tt == T - 1) asm volatile("s_waitcnt vmcnt(0)" ::: "memory");
        else             asm volatile("s_waitcnt vmcnt(4)" ::: "memory");
      }
      if (p == 3) {                   // publish slab 2tt+2 for next tile's p0 reads
        if (tt < T - 2)       asm volatile("s_waitcnt vmcnt(6)" ::: "memory");
        else if (tt == T - 2) asm volatile("s_waitcnt vmcnt(4)" ::: "memory");
        // tt == T-1: loop ends, no wait needed
      }
      __builtin_amdgcn_s_barrier();
    }
  }

  const signed char* mb = mT + (size_t)zb * sMb;
#pragma unroll
  for (int mi = 0; mi < 8; ++mi) {
#pragma unroll
    for (int ni = 0; ni < 4; ++ni) {
      const int col = n0 + wn * 64 + ni * 16 + fr;
#pragma unroll
      for (int i = 0; i < 4; ++i) {
        const int r = m0 + wm * 128 + mi * 16 + fg * 4 + i;  // C/D: row=(lane>>4)*4+i, col=lane&15
        float v = acc[mi][ni][i] * scale;
        if constexpr (BIAS_MODE == 1) v += bias[col];
        if constexpr (BIAS_MODE == 2) v += bias[r];
        if constexpr (MASK) v += -1e9f * (float)mb[(size_t)r * N + col];
        if constexpr (GELU) v = 0.5f * v * (1.0f + erff(v * 0.70710678118f));
        const size_t off = (size_t)zb * sCb + (size_t)r * ldc + col;
        if constexpr (OUT_BF16) ((bf16*)Cout)[off] = (bf16)v;
        else                    ((float*)Cout)[off] = v;
      }
    }
  }
}

// ---------------- f32 -> bf16 bulk convert (8 elems/thread/iter)
__global__ __launch_bounds__(256)
void conv_k(const float* __restrict__ in, bf16* __restrict__ out, long n8)
{
  for (long i = blockIdx.x * 256 + threadIdx.x; i < n8; i += (long)gridDim.x * 256) {
    f32x4 a = *(const f32x4*)(in + i * 8);
    f32x4 b = *(const f32x4*)(in + i * 8 + 4);
    bf16x8 o;
#pragma unroll
    for (int j = 0; j < 4; ++j) { o[j] = (bf16)a[j]; o[4 + j] = (bf16)b[j]; }
    *(bf16x8*)(out + i * 8) = o;
  }
}

// ---------------- weight transpose+convert: out[n][k] = (bf16)W[k][n], 1024x1024, z selects weight
__global__ __launch_bounds__(256)
void wtrans_k(const float* __restrict__ W0, const float* __restrict__ W1,
              const float* __restrict__ W2, const float* __restrict__ W3,
              bf16* __restrict__ out)
{
  const float* Ws[4] = {W0, W1, W2, W3};
  const float* W = Ws[blockIdx.z];
  bf16* o = out + (size_t)blockIdx.z * (1024 * 1024);
  __shared__ bf16 tile[64][72];
  const int t  = threadIdx.x;
  const int c0 = blockIdx.x * 64;
  const int r0 = blockIdx.y * 64;
  {
    const int rr = t >> 2;
    const int cc = (t & 3) * 16;
    const float* src = W + (size_t)(r0 + rr) * 1024 + c0 + cc;
#pragma unroll
    for (int j = 0; j < 16; j += 4) {
      f32x4 v = *(const f32x4*)(src + j);
#pragma unroll
      for (int i = 0; i < 4; ++i) tile[cc + j + i][rr] = (bf16)v[i];
    }
  }
  __syncthreads();
  {
    const int nr = t >> 2;
    const int kc = (t & 3) * 16;
    bf16* dst = o + (size_t)(c0 + nr) * 1024 + r0 + kc;
    *(bf16x8*)dst       = *(const bf16x8*)&tile[nr][kc];
    *(bf16x8*)(dst + 8) = *(const bf16x8*)&tile[nr][kc + 8];
  }
}

// ---------------- mask transpose: maskT[b][k][q] = (int8)mask[b][q][k]
__global__ __launch_bounds__(256)
void maskT_k(const int* __restrict__ mask, signed char* __restrict__ mT)
{
  __shared__ signed char tile[64][65];
  const int t  = threadIdx.x;
  const int b  = blockIdx.z;
  const int k0 = blockIdx.x * 64;
  const int q0 = blockIdx.y * 64;
  {
    const int iq = t >> 2;
    const int ic = (t & 3) * 16;
    const int* src = mask + ((size_t)b * 2048 + q0 + iq) * 2048 + k0 + ic;
#pragma unroll
    for (int j = 0; j < 16; j += 4) {
      int4 v = *(const int4*)(src + j);
      tile[ic + j + 0][iq] = (signed char)v.x;
      tile[ic + j + 1][iq] = (signed char)v.y;
      tile[ic + j + 2][iq] = (signed char)v.z;
      tile[ic + j + 3][iq] = (signed char)v.w;
    }
  }
  __syncthreads();
  {
    const int ik = t >> 2;
    const int iq = (t & 3) * 16;
    signed char* dst = mT + ((size_t)b * 2048 + k0 + ik) * 2048 + q0 + iq;
#pragma unroll
    for (int j = 0; j < 16; ++j) dst[j] = tile[ik][iq + j];
  }
}

// ---------------- row softmax: read bf16 scores from first 4KB of each 8KB row slot,
// write f32 attn (full slot, in place) + compact bf16 copy.
__global__ __launch_bounds__(256)
void softmax_rows_k(float* __restrict__ P, bf16* __restrict__ Pb)
{
  char* slot = (char*)P + (size_t)blockIdx.x * 8192;
  const bf16* pin = (const bf16*)slot;
  float* pout = (float*)slot;
  bf16* pb = Pb + (size_t)blockIdx.x * 2048;
  const int t = threadIdx.x;
  const int wave = t >> 6, lane = t & 63;
  bf16x8 raw = *(const bf16x8*)(pin + t * 8);
  float v[8];
#pragma unroll
  for (int j = 0; j < 8; ++j) v[j] = (float)raw[j];
  float m = -3e38f;
#pragma unroll
  for (int j = 0; j < 8; ++j) m = fmaxf(m, v[j]);
#pragma unroll
  for (int off = 32; off; off >>= 1) m = fmaxf(m, __shfl_xor(m, off));
  __shared__ float red[8];
  if (lane == 0) red[wave] = m;
  __syncthreads();
  m = fmaxf(fmaxf(red[0], red[1]), fmaxf(red[2], red[3]));
  float s = 0.0f;
#pragma unroll
  for (int j = 0; j < 8; ++j) { v[j] = __expf(v[j] - m); s += v[j]; }
#pragma unroll
  for (int off = 32; off; off >>= 1) s += __shfl_xor(s, off);
  if (lane == 0) red[4 + wave] = s;
  __syncthreads();
  s = red[4] + red[5] + red[6] + red[7];
  const float inv = 1.0f / s;
  f32x4 o0, o1;
  bf16x8 ob;
#pragma unroll
  for (int j = 0; j < 4; ++j) {
    o0[j] = v[j] * inv; o1[j] = v[4 + j] * inv;
    ob[j] = (bf16)o0[j]; ob[4 + j] = (bf16)o1[j];
  }
  __syncthreads();   // all reads of this row's bf16 done before overwrite (paranoia; in-regs anyway)
  *(f32x4*)(pout + t * 8)     = o0;
  *(f32x4*)(pout + t * 8 + 4) = o1;
  *(bf16x8*)(pb + t * 8)      = ob;
}

// ---------------- LayerNorm over 1024, bf16 input (one block per row)
__global__ __launch_bounds__(256)
void ln_k(const bf16* __restrict__ g, const float* __restrict__ gamma,
          const float* __restrict__ beta, float* __restrict__ out)
{
  const bf16* p = g + (size_t)blockIdx.x * 1024;
  const int t = threadIdx.x;
  const int wave = t >> 6, lane = t & 63;
  bf16x4 raw = *(const bf16x4*)(p + t * 4);
  f32x4 v;
#pragma unroll
  for (int j = 0; j < 4; ++j) v[j] = (float)raw[j];
  float s = v[0] + v[1] + v[2] + v[3];
  float q = v[0]*v[0] + v[1]*v[1] + v[2]*v[2] + v[3]*v[3];
#pragma unroll
  for (int off = 32; off; off >>= 1) { s += __shfl_xor(s, off); q += __shfl_xor(q, off); }
  __shared__ float red[16];
  if (lane == 0) { red[wave] = s; red[8 + wave] = q; }
  __syncthreads();
  s = red[0] + red[1] + red[2] + red[3];
  q = red[8] + red[9] + red[10] + red[11];
  const float mu   = s * (1.0f / 1024.0f);
  const float var  = q * (1.0f / 1024.0f) - mu * mu;
  const float rstd = rsqrtf(var + 1e-5f);
  f32x4 gm = *(const f32x4*)(gamma + t * 4);
  f32x4 bt = *(const f32x4*)(beta + t * 4);
  f32x4 o;
#pragma unroll
  for (int j = 0; j < 4; ++j) o[j] = (v[j] - mu) * rstd * gm[j] + bt[j];
  *(f32x4*)(out + (size_t)blockIdx.x * 1024 + t * 4) = o;
}

extern "C" void kernel_launch(void* const* d_in, const int* in_sizes, int n_in,
                              void* d_out, int out_size, void* d_ws, size_t ws_size,
                              hipStream_t stream)
{
  const float* Q     = (const float*)d_in[0];
  const float* Kin   = (const float*)d_in[1];
  const float* V     = (const float*)d_in[2];
  const int*   mask  = (const int*)d_in[3];
  const float* Wq    = (const float*)d_in[4];
  const float* bq    = (const float*)d_in[5];
  const float* Wk    = (const float*)d_in[6];
  const float* bk    = (const float*)d_in[7];
  const float* Wv    = (const float*)d_in[8];
  const float* bv    = (const float*)d_in[9];
  const float* Wo    = (const float*)d_in[10];
  const float* bo    = (const float*)d_in[11];
  const float* gamma = (const float*)d_in[12];
  const float* beta  = (const float*)d_in[13];

  float* outCtx  = (float*)d_out;                      // [8,2048,1024]
  float* outAttn = outCtx + (size_t)8 * 2048 * 1024;   // [8,2048,2048] (k,q); 8KB row slots

  // workspace (MiB offsets), peak 136 MiB:
  // wts   [0,8)      whole run
  // qp    [8,40)     dead after QKT -> wvT output reuses
  // kp    [40,72)    dead after QKT -+
  // Qb    [72,104)   dead after qp  -> mT reuses; mT dead after QKT -+-> attnb [40,104)
  // Kb    [104,136)  dead after kp  -> Vb; Vb dead after wvT -> ctx
  // attnb [40,104)   dead after PV  -> g bf16 [40,72)
  char* ws = (char*)d_ws;
  const size_t MB = 1048576;
  bf16*        wts   = (bf16*)(ws + 0 * MB);
  bf16*        qp    = (bf16*)(ws + 8 * MB);
  bf16*        kp    = (bf16*)(ws + 40 * MB);
  bf16*        Qb    = (bf16*)(ws + 72 * MB);
  bf16*        Kb    = (bf16*)(ws + 104 * MB);
  signed char* mT    = (signed char*)(ws + 72 * MB);
  bf16*        attnb = (bf16*)(ws + 40 * MB);
  bf16*        wvT   = (bf16*)(ws + 8 * MB);
  bf16*        Vb    = (bf16*)(ws + 104 * MB);
  bf16*        ctx   = (bf16*)(ws + 104 * MB);
  bf16*        g     = (bf16*)(ws + 40 * MB);
  bf16* Wqt = wts;
  bf16* Wkt = wts + 1 * 1024 * 1024;
  bf16* Wvt = wts + 2 * 1024 * 1024;
  bf16* Wot = wts + 3 * 1024 * 1024;

  const dim3 blk(256);
  const dim3 blk8(512);
  const long n8 = (long)16384 * 1024 / 8;

  // 1. weights -> bf16 transposed
  wtrans_k<<<dim3(16, 16, 4), blk, 0, stream>>>(Wq, Wk, Wv, Wo, wts);
  // 2. Q,K -> bf16
  conv_k<<<dim3(2048), blk, 0, stream>>>(Q, Qb, n8);
  conv_k<<<dim3(2048), blk, 0, stream>>>(Kin, Kb, n8);
  // 3. qp = Qb @ Wqt + bq ; kp = Kb @ Wkt + bk
  bgemm8_k<1, false, false, true><<<dim3(4, 64, 1), blk8, 0, stream>>>(
      Qb, Wqt, bq, nullptr, qp, 1024, 1024, 1024, 0, 0, 0, 0, 1.0f);
  bgemm8_k<1, false, false, true><<<dim3(4, 64, 1), blk8, 0, stream>>>(
      Kb, Wkt, bk, nullptr, kp, 1024, 1024, 1024, 0, 0, 0, 0, 1.0f);
  // 4. V -> bf16 (into Kb slot, Kb now dead)
  conv_k<<<dim3(2048), blk, 0, stream>>>(V, Vb, n8);
  // 5. mask transpose (into Qb slot, Qb now dead)
  maskT_k<<<dim3(32, 32, 8), blk, 0, stream>>>(mask, mT);
  // 6. scores bf16 into first 4KB of each attn row slot: ldc=4096 bf16 elems
  bgemm8_k<0, true, false, true><<<dim3(8, 8, 8), blk8, 0, stream>>>(
      kp, qp, nullptr, mT, (bf16*)outAttn, 2048, 4096, 1024,
      (long)2048 * 1024, (long)2048 * 1024, (long)2048 * 4096, (long)2048 * 2048, 0.03125f);
  // 7. wvT[b][v][q] = Wvt @ Vb^T + bv (per-row); overwrites qp (dead)
  bgemm8_k<2, false, false, true><<<dim3(8, 4, 8), blk8, 0, stream>>>(
      Wvt, Vb, bv, nullptr, wvT, 2048, 2048, 1024,
      0, (long)2048 * 1024, (long)1024 * 2048, 0, 1.0f);
  // 8. softmax: bf16 scores -> f32 attn (in slot) + bf16 attnb
  softmax_rows_k<<<dim3(16384), blk, 0, stream>>>(outAttn, attnb);
  // 9. ctx[b][k][v] = sum_q attnb[k][q] * wvT[v][q]
  bgemm8_k<0, false, false, true><<<dim3(4, 8, 8), blk8, 0, stream>>>(
      attnb, wvT, nullptr, nullptr, ctx, 1024, 1024, 2048,
      (long)2048 * 2048, (long)1024 * 2048, (long)2048 * 1024, 0, 1.0f);
  // 10. g = gelu(ctx @ Wot + bo), bf16
  bgemm8_k<1, false, true, true><<<dim3(4, 64, 1), blk8, 0, stream>>>(
      ctx, Wot, bo, nullptr, g, 1024, 1024, 1024, 0, 0, 0, 0, 1.0f);
  // 11. LayerNorm -> context output
  ln_k<<<dim3(16384), blk, 0, stream>>>(g, gamma, beta, outCtx);
}

// Round 6
// 489.638 us; speedup vs baseline: 1.6462x; 1.0331x over previous
//
#include <hip/hip_runtime.h>
#include <math.h>

typedef __bf16 bf16;
typedef __bf16 bf16x8 __attribute__((ext_vector_type(8)));
typedef __bf16 bf16x4 __attribute__((ext_vector_type(4)));
typedef float f32x4 __attribute__((ext_vector_type(4)));
typedef signed char schar8 __attribute__((ext_vector_type(8)));

// ---- async global->LDS, 16B per lane. LDS dest = wave-uniform base (+lane*16 implicit).
__device__ inline void gload16(const void* g, void* l) {
  typedef __attribute__((address_space(1))) const unsigned int guint;
  typedef __attribute__((address_space(3))) unsigned int luint;
  __builtin_amdgcn_global_load_lds((guint*)g, (luint*)l, 16, 0, 0);
}

// ================= 256x256 8-phase GEMM (T1 XCD-swizzle, T2 LDS swizzle,
// T3/T4 counted-vmcnt pipeline, T5 setprio). 512 threads = 8 waves (2Mx4N),
// per-wave output 128x64 (acc[8][4]), mfma 16x16x32 bf16.
// LDS ring of 4 slots per operand (4 x 8192 bf16 = 16KB each, 64KB/operand).
// Epilogue (OUT_BF16): per-wave LDS repack (16B-granule XOR swizzle) ->
// 16 coalesced dwordx4 stores/thread; MASK applied vectorized in readback.
// C[m][n] = op(scale * sum_k A[m][k]*B[n][k] + bias +/- mask); C row stride = ldc.
// bias2: if non-null, used instead of bias when blockIdx.z==1 (merged launches).
template<int BIAS_MODE, bool MASK, bool GELU, bool OUT_BF16>
__global__ __launch_bounds__(512, 2)
void bgemm8_k(const bf16* __restrict__ A, const bf16* __restrict__ B,
              const float* __restrict__ bias, const float* __restrict__ bias2,
              const signed char* __restrict__ mT,
              void* __restrict__ Cout, int N, int ldc, int K,
              long sAb, long sBb, long sCb, long sMb, float scale)
{
  __shared__ __align__(16) char smem[131072];
  bf16* As = (bf16*)smem;              // [4 slots][256][32] bf16 (slot stride 8192 elems!)
  bf16* Bs = (bf16*)(smem + 65536);

  const int t    = threadIdx.x;
  const int zb   = blockIdx.z;
  const int gx   = gridDim.x;
  const int nwg  = gx * gridDim.y;
  const int orig = blockIdx.y * gx + blockIdx.x;
  const int swz  = (orig & 7) * (nwg >> 3) + (orig >> 3);   // nwg % 8 == 0 always here
  const int m0   = (swz / gx) * 256;
  const int n0   = (swz % gx) * 256;

  const float* bp = (BIAS_MODE && bias2 && zb) ? bias2 : bias;

  const int wave = t >> 6;
  const int lane = t & 63;
  const int wm = wave >> 2;          // 0..1 -> rows wm*128..+128
  const int wn = wave & 3;           // 0..3 -> cols wn*64..+64
  const int fr = lane & 15;
  const int fg = lane >> 4;          // 0..3

  // ---- staging constants (2 issues per thread per half-slab)
  const bf16* Abase = A + (size_t)zb * sAb + (size_t)m0 * K;
  const bf16* Bbase = B + (size_t)zb * sBb + (size_t)n0 * K;
  size_t gOff[2];
  int    ldsOff[2];
#pragma unroll
  for (int j = 0; j < 2; ++j) {
    const int L   = j * 8192 + t * 16;   // byte offset within 16KB slab-part
    const int row = L >> 6;              // 0..255
    const int gp  = (L >> 4) & 3;        // linear LDS granule
    const int g   = gp ^ ((row >> 1) & 3);   // pre-swizzled global granule
    gOff[j]   = (size_t)row * K + (size_t)g * 8;
    ldsOff[j] = j * 4096 + wave * 512;   // elements; wave-uniform; HW adds lane*16B
  }
  const int HMAX = (K >> 5) * 2;   // 2 half-slabs per 32-wide slab

  auto stage = [&](int H) {
    if (H >= HMAX) return;
    const int s    = H >> 1;
    const int slot = s & 3;
    const size_t kof = (size_t)s * 32;
    if ((H & 1) == 0) {
      gload16(Abase + kof + gOff[0], As + slot * 8192 + ldsOff[0]);
      gload16(Abase + kof + gOff[1], As + slot * 8192 + ldsOff[1]);
    } else {
      gload16(Bbase + kof + gOff[0], Bs + slot * 8192 + ldsOff[0]);
      gload16(Bbase + kof + gOff[1], Bs + slot * 8192 + ldsOff[1]);
    }
  };

  // ---- fragment read offsets (swizzled): row base multiple of 16 -> xor is (fr>>1)&3
  const int xsw  = (fg ^ ((fr >> 1) & 3)) * 8;
  const int aoff = (wm * 128 + fr) * 32 + xsw;
  const int boff = (wn * 64 + fr) * 32 + xsw;

  f32x4 acc[8][4] = {};
  const int T = K >> 6;   // K-tiles of 64

  // prologue: A(s0),B(s0),A(s1),B(s1),A(s2); need slab 0 (H<=1) -> vmcnt(6)
  stage(0); stage(1); stage(2); stage(3); stage(4);
  asm volatile("s_waitcnt vmcnt(6)" ::: "memory");
  __builtin_amdgcn_s_barrier();

  for (int tt = 0; tt < T; ++tt) {
#pragma unroll
    for (int p = 0; p < 4; ++p) {
      const int kk   = p & 1;        // k-half of this K-tile (32-slab)
      const int oh   = p >> 1;       // output half (mi 0-3 / 4-7)
      const int slot = (2 * tt + kk) & 3;
      bf16x8 af[4], bfv[4];
#pragma unroll
      for (int i = 0; i < 4; ++i)
        af[i]  = *(const bf16x8*)(As + slot * 8192 + aoff + (oh * 4 + i) * 512);
#pragma unroll
      for (int i = 0; i < 4; ++i)
        bfv[i] = *(const bf16x8*)(Bs + slot * 8192 + boff + i * 512);
      stage(4 * tt + p + 5);         // one half-slab, 5 phases ahead of first use
      __builtin_amdgcn_s_barrier();
      __builtin_amdgcn_s_setprio(1);
#pragma unroll
      for (int mi = 0; mi < 4; ++mi)
#pragma unroll
        for (int ni = 0; ni < 4; ++ni)
          acc[oh * 4 + mi][ni] =
            __builtin_amdgcn_mfma_f32_16x16x32_bf16(af[mi], bfv[ni], acc[oh * 4 + mi][ni], 0, 0, 0);
      __builtin_amdgcn_s_setprio(0);
      if (p == 0) {                   // publish slab 2tt+1 for p1 reads
        if (tt == T - 1) asm volatile("s_waitcnt vmcnt(0)" ::: "memory");
        else             asm volatile("s_waitcnt vmcnt(4)" ::: "memory");
      }
      if (p == 3) {                   // publish slab 2tt+2 for next tile's p0 reads
        if (tt < T - 2)       asm volatile("s_waitcnt vmcnt(6)" ::: "memory");
        else if (tt == T - 2) asm volatile("s_waitcnt vmcnt(4)" ::: "memory");
      }
      __builtin_amdgcn_s_barrier();
    }
  }

  if constexpr (OUT_BF16) {
    // ---- epilogue: per-wave 16KB LDS repack, 16B-chunk XOR swizzle.
    // write chunk = (cb>>4)^(r&7); read chunk cg fetches (cg^(r&7)) -> cb>>4 == cg.
    bf16* wbuf = (bf16*)(smem + wave * 16384);   // [128 rows][128 bytes]
#pragma unroll
    for (int mi = 0; mi < 8; ++mi) {
#pragma unroll
      for (int ni = 0; ni < 4; ++ni) {
        const int col = n0 + wn * 64 + ni * 16 + fr;
#pragma unroll
        for (int i = 0; i < 4; ++i) {
          const int r = mi * 16 + fg * 4 + i;     // local row 0..127
          float v = acc[mi][ni][i] * scale;
          if constexpr (BIAS_MODE == 1) v += bp[col];
          if constexpr (BIAS_MODE == 2) v += bp[m0 + wm * 128 + r];
          if constexpr (GELU) v = 0.5f * v * (1.0f + erff(v * 0.70710678118f));
          const int cb = ni * 32 + fr * 2;        // byte col 0..126
          *(bf16*)((char*)wbuf + r * 128 + (cb ^ ((r & 7) << 4))) = (bf16)v;
        }
      }
    }
    __syncthreads();   // make repack writes visible before readback (uniform: all 8 waves here)
    const int rowbase = m0 + wm * 128;
    const int colbase = n0 + wn * 64;
    const signed char* mb = MASK ? (mT + (size_t)zb * sMb) : nullptr;
#pragma unroll
    for (int j = 0; j < 16; ++j) {
      const int r  = j * 8 + (lane >> 3);
      const int cg = lane & 7;                    // global 16B chunk within 128B row
      bf16x8 val = *(const bf16x8*)((char*)wbuf + r * 128 + ((cg << 4) ^ ((r & 7) << 4)));
      const int grow = rowbase + r;
      const int gcol = colbase + cg * 8;
      if constexpr (MASK) {
        schar8 mk = *(const schar8*)(mb + (size_t)grow * N + gcol);
#pragma unroll
        for (int e = 0; e < 8; ++e)
          val[e] = (bf16)((float)val[e] + -1e9f * (float)mk[e]);
      }
      *(bf16x8*)((bf16*)Cout + (size_t)zb * sCb + (size_t)grow * ldc + gcol) = val;
    }
  } else {
    // f32 direct stores
#pragma unroll
    for (int mi = 0; mi < 8; ++mi) {
#pragma unroll
      for (int ni = 0; ni < 4; ++ni) {
        const int col = n0 + wn * 64 + ni * 16 + fr;
#pragma unroll
        for (int i = 0; i < 4; ++i) {
          const int r = m0 + wm * 128 + mi * 16 + fg * 4 + i;
          float v = acc[mi][ni][i] * scale;
          if constexpr (BIAS_MODE == 1) v += bp[col];
          if constexpr (BIAS_MODE == 2) v += bp[r];
          if constexpr (GELU) v = 0.5f * v * (1.0f + erff(v * 0.70710678118f));
          ((float*)Cout)[(size_t)zb * sCb + (size_t)r * ldc + col] = v;
        }
      }
    }
  }
}

// ---------------- f32 -> bf16 bulk convert; z selects (in0->out0, in1->out1)
__global__ __launch_bounds__(256)
void conv2_k(const float* __restrict__ i0, const float* __restrict__ i1,
             bf16* __restrict__ o0, bf16* __restrict__ o1, long n8)
{
  const float* in = blockIdx.z ? i1 : i0;
  bf16* out = blockIdx.z ? o1 : o0;
  for (long i = blockIdx.x * 256 + threadIdx.x; i < n8; i += (long)gridDim.x * 256) {
    f32x4 a = *(const f32x4*)(in + i * 8);
    f32x4 b = *(const f32x4*)(in + i * 8 + 4);
    bf16x8 o;
#pragma unroll
    for (int j = 0; j < 4; ++j) { o[j] = (bf16)a[j]; o[4 + j] = (bf16)b[j]; }
    *(bf16x8*)(out + i * 8) = o;
  }
}

// ---------------- weight transpose+convert: out[n][k] = (bf16)W[k][n], 1024x1024, z selects weight
__global__ __launch_bounds__(256)
void wtrans_k(const float* __restrict__ W0, const float* __restrict__ W1,
              const float* __restrict__ W2, const float* __restrict__ W3,
              bf16* __restrict__ out)
{
  const float* Ws[4] = {W0, W1, W2, W3};
  const float* W = Ws[blockIdx.z];
  bf16* o = out + (size_t)blockIdx.z * (1024 * 1024);
  __shared__ bf16 tile[64][72];
  const int t  = threadIdx.x;
  const int c0 = blockIdx.x * 64;
  const int r0 = blockIdx.y * 64;
  {
    const int rr = t >> 2;
    const int cc = (t & 3) * 16;
    const float* src = W + (size_t)(r0 + rr) * 1024 + c0 + cc;
#pragma unroll
    for (int j = 0; j < 16; j += 4) {
      f32x4 v = *(const f32x4*)(src + j);
#pragma unroll
      for (int i = 0; i < 4; ++i) tile[cc + j + i][rr] = (bf16)v[i];
    }
  }
  __syncthreads();
  {
    const int nr = t >> 2;
    const int kc = (t & 3) * 16;
    bf16* dst = o + (size_t)(c0 + nr) * 1024 + r0 + kc;
    *(bf16x8*)dst       = *(const bf16x8*)&tile[nr][kc];
    *(bf16x8*)(dst + 8) = *(const bf16x8*)&tile[nr][kc + 8];
  }
}

// ---------------- mask transpose: maskT[b][k][q] = (int8)mask[b][q][k]
__global__ __launch_bounds__(256)
void maskT_k(const int* __restrict__ mask, signed char* __restrict__ mT)
{
  __shared__ signed char tile[64][65];
  const int t  = threadIdx.x;
  const int b  = blockIdx.z;
  const int k0 = blockIdx.x * 64;
  const int q0 = blockIdx.y * 64;
  {
    const int iq = t >> 2;
    const int ic = (t & 3) * 16;
    const int* src = mask + ((size_t)b * 2048 + q0 + iq) * 2048 + k0 + ic;
#pragma unroll
    for (int j = 0; j < 16; j += 4) {
      int4 v = *(const int4*)(src + j);
      tile[ic + j + 0][iq] = (signed char)v.x;
      tile[ic + j + 1][iq] = (signed char)v.y;
      tile[ic + j + 2][iq] = (signed char)v.z;
      tile[ic + j + 3][iq] = (signed char)v.w;
    }
  }
  __syncthreads();
  {
    const int ik = t >> 2;
    const int iq = (t & 3) * 16;
    signed char* dst = mT + ((size_t)b * 2048 + k0 + ik) * 2048 + q0 + iq;
#pragma unroll
    for (int j = 0; j < 16; ++j) dst[j] = tile[ik][iq + j];
  }
}

// ---------------- row softmax: read bf16 scores from first 4KB of each 8KB row slot,
// write f32 attn (full slot, in place) + compact bf16 copy.
__global__ __launch_bounds__(256)
void softmax_rows_k(float* __restrict__ P, bf16* __restrict__ Pb)
{
  char* slot = (char*)P + (size_t)blockIdx.x * 8192;
  const bf16* pin = (const bf16*)slot;
  float* pout = (float*)slot;
  bf16* pb = Pb + (size_t)blockIdx.x * 2048;
  const int t = threadIdx.x;
  const int wave = t >> 6, lane = t & 63;
  bf16x8 raw = *(const bf16x8*)(pin + t * 8);
  float v[8];
#pragma unroll
  for (int j = 0; j < 8; ++j) v[j] = (float)raw[j];
  float m = -3e38f;
#pragma unroll
  for (int j = 0; j < 8; ++j) m = fmaxf(m, v[j]);
#pragma unroll
  for (int off = 32; off; off >>= 1) m = fmaxf(m, __shfl_xor(m, off));
  __shared__ float red[8];
  if (lane == 0) red[wave] = m;
  __syncthreads();
  m = fmaxf(fmaxf(red[0], red[1]), fmaxf(red[2], red[3]));
  float s = 0.0f;
#pragma unroll
  for (int j = 0; j < 8; ++j) { v[j] = __expf(v[j] - m); s += v[j]; }
#pragma unroll
  for (int off = 32; off; off >>= 1) s += __shfl_xor(s, off);
  if (lane == 0) red[4 + wave] = s;
  __syncthreads();
  s = red[4] + red[5] + red[6] + red[7];
  const float inv = 1.0f / s;
  f32x4 o0, o1;
  bf16x8 ob;
#pragma unroll
  for (int j = 0; j < 4; ++j) {
    o0[j] = v[j] * inv; o1[j] = v[4 + j] * inv;
    ob[j] = (bf16)o0[j]; ob[4 + j] = (bf16)o1[j];
  }
  *(f32x4*)(pout + t * 8)     = o0;
  *(f32x4*)(pout + t * 8 + 4) = o1;
  *(bf16x8*)(pb + t * 8)      = ob;
}

// ---------------- LayerNorm over 1024, bf16 input (one block per row)
__global__ __launch_bounds__(256)
void ln_k(const bf16* __restrict__ g, const float* __restrict__ gamma,
          const float* __restrict__ beta, float* __restrict__ out)
{
  const bf16* p = g + (size_t)blockIdx.x * 1024;
  const int t = threadIdx.x;
  const int wave = t >> 6, lane = t & 63;
  bf16x4 raw = *(const bf16x4*)(p + t * 4);
  f32x4 v;
#pragma unroll
  for (int j = 0; j < 4; ++j) v[j] = (float)raw[j];
  float s = v[0] + v[1] + v[2] + v[3];
  float q = v[0]*v[0] + v[1]*v[1] + v[2]*v[2] + v[3]*v[3];
#pragma unroll
  for (int off = 32; off; off >>= 1) { s += __shfl_xor(s, off); q += __shfl_xor(q, off); }
  __shared__ float red[16];
  if (lane == 0) { red[wave] = s; red[8 + wave] = q; }
  __syncthreads();
  s = red[0] + red[1] + red[2] + red[3];
  q = red[8] + red[9] + red[10] + red[11];
  const float mu   = s * (1.0f / 1024.0f);
  const float var  = q * (1.0f / 1024.0f) - mu * mu;
  const float rstd = rsqrtf(var + 1e-5f);
  f32x4 gm = *(const f32x4*)(gamma + t * 4);
  f32x4 bt = *(const f32x4*)(beta + t * 4);
  f32x4 o;
#pragma unroll
  for (int j = 0; j < 4; ++j) o[j] = (v[j] - mu) * rstd * gm[j] + bt[j];
  *(f32x4*)(out + (size_t)blockIdx.x * 1024 + t * 4) = o;
}

extern "C" void kernel_launch(void* const* d_in, const int* in_sizes, int n_in,
                              void* d_out, int out_size, void* d_ws, size_t ws_size,
                              hipStream_t stream)
{
  const float* Q     = (const float*)d_in[0];
  const float* Kin   = (const float*)d_in[1];
  const float* V     = (const float*)d_in[2];
  const int*   mask  = (const int*)d_in[3];
  const float* Wq    = (const float*)d_in[4];
  const float* bq    = (const float*)d_in[5];
  const float* Wk    = (const float*)d_in[6];
  const float* bk    = (const float*)d_in[7];
  const float* Wv    = (const float*)d_in[8];
  const float* bv    = (const float*)d_in[9];
  const float* Wo    = (const float*)d_in[10];
  const float* bo    = (const float*)d_in[11];
  const float* gamma = (const float*)d_in[12];
  const float* beta  = (const float*)d_in[13];

  float* outCtx  = (float*)d_out;                      // [8,2048,1024]
  float* outAttn = outCtx + (size_t)8 * 2048 * 1024;   // [8,2048,2048] (k,q); 8KB row slots

  // workspace (MiB offsets), peak 136 MiB:
  // wts   [0,8)      whole run
  // qp    [8,40)     dead after QKT -> wvT output reuses
  // kp    [40,72)    dead after QKT
  // Qb    [72,104)   dead after proj -> mT reuses; mT dead after QKT
  // Kb    [104,136)  dead after proj -> Vb; Vb dead after wvT -> ctx
  // attnb [40,104)   (over kp+mT, both dead) dead after PV -> g bf16 [40,72)
  char* ws = (char*)d_ws;
  const size_t MB = 1048576;
  bf16*        wts   = (bf16*)(ws + 0 * MB);
  bf16*        qp    = (bf16*)(ws + 8 * MB);
  bf16*        kp    = (bf16*)(ws + 40 * MB);
  bf16*        Qb    = (bf16*)(ws + 72 * MB);
  bf16*        Kb    = (bf16*)(ws + 104 * MB);
  signed char* mT    = (signed char*)(ws + 72 * MB);
  bf16*        attnb = (bf16*)(ws + 40 * MB);
  bf16*        wvT   = (bf16*)(ws + 8 * MB);
  bf16*        Vb    = (bf16*)(ws + 104 * MB);
  bf16*        ctx   = (bf16*)(ws + 104 * MB);
  bf16*        g     = (bf16*)(ws + 40 * MB);
  bf16* Wqt = wts;
  bf16* Wkt = wts + 1 * 1024 * 1024;
  bf16* Wvt = wts + 2 * 1024 * 1024;
  bf16* Wot = wts + 3 * 1024 * 1024;

  const dim3 blk(256);
  const dim3 blk8(512);
  const long n8 = (long)16384 * 1024 / 8;

  // 1. weights -> bf16 transposed
  wtrans_k<<<dim3(16, 16, 4), blk, 0, stream>>>(Wq, Wk, Wv, Wo, wts);
  // 2. Q,K -> bf16 (one launch, z=2)
  conv2_k<<<dim3(2048, 1, 2), blk, 0, stream>>>(Q, Kin, Qb, Kb, n8);
  // 3. merged projections: z=0 qp = Qb@Wqt+bq ; z=1 kp = Kb@Wkt+bk
  bgemm8_k<1, false, false, true><<<dim3(4, 64, 2), blk8, 0, stream>>>(
      Qb, Wqt, bq, bk, nullptr, qp, 1024, 1024, 1024,
      16777216, 1048576, 16777216, 0, 1.0f);
  // 4. V -> bf16 (into Kb slot, Kb now dead)
  conv2_k<<<dim3(2048, 1, 1), blk, 0, stream>>>(V, nullptr, Vb, nullptr, n8);
  // 5. mask transpose (into Qb slot, Qb now dead)
  maskT_k<<<dim3(32, 32, 8), blk, 0, stream>>>(mask, mT);
  // 6. scores bf16 into first 4KB of each attn row slot: ldc=4096 bf16 elems
  bgemm8_k<0, true, false, true><<<dim3(8, 8, 8), blk8, 0, stream>>>(
      kp, qp, nullptr, nullptr, mT, (bf16*)outAttn, 2048, 4096, 1024,
      (long)2048 * 1024, (long)2048 * 1024, (long)2048 * 4096, (long)2048 * 2048, 0.03125f);
  // 7. wvT[b][v][q] = Wvt @ Vb^T + bv (per-row); overwrites qp (dead)
  bgemm8_k<2, false, false, true><<<dim3(8, 4, 8), blk8, 0, stream>>>(
      Wvt, Vb, bv, nullptr, nullptr, wvT, 2048, 2048, 1024,
      0, (long)2048 * 1024, (long)1024 * 2048, 0, 1.0f);
  // 8. softmax: bf16 scores -> f32 attn (in slot) + bf16 attnb
  softmax_rows_k<<<dim3(16384), blk, 0, stream>>>(outAttn, attnb);
  // 9. ctx[b][k][v] = sum_q attnb[k][q] * wvT[v][q]
  bgemm8_k<0, false, false, true><<<dim3(4, 8, 8), blk8, 0, stream>>>(
      attnb, wvT, nullptr, nullptr, nullptr, ctx, 1024, 1024, 2048,
      (long)2048 * 2048, (long)1024 * 2048, (long)2048 * 1024, 0, 1.0f);
  // 10. g = gelu(ctx @ Wot + bo), bf16
  bgemm8_k<1, false, true, true><<<dim3(4, 64, 1), blk8, 0, stream>>>(
      ctx, Wot, bo, nullptr, nullptr, g, 1024, 1024, 1024, 0, 0, 0, 0, 1.0f);
  // 11. LayerNorm -> context output
  ln_k<<<dim3(16384), blk, 0, stream>>>(g, gamma, beta, outCtx);
}